// Round 1
// 1966.335 us; speedup vs baseline: 1.2384x; 1.2384x over previous
//
#include <hip/hip_runtime.h>

// Problem constants
#define BB 4
#define SS 2048
#define DD 768
#define HH 12
#define DKV 64
#define NEGBIG (-1e30f)

typedef float f32x4 __attribute__((ext_vector_type(4)));
typedef short bf16x8 __attribute__((ext_vector_type(8)));
typedef short s16x4 __attribute__((ext_vector_type(4)));

__device__ inline unsigned short f2bf(float f) {
  unsigned u = __builtin_bit_cast(unsigned, f);
  u += 0x7fffu + ((u >> 16) & 1u);   // RNE
  return (unsigned short)(u >> 16);
}

// ---------------------------------------------------------------------------
// Projection GEMM (unchanged, fp32): out[b,h,s,d] = X @ W + bias
// ---------------------------------------------------------------------------
__global__ __launch_bounds__(256) void proj_gemm(
    const float* __restrict__ X, const float* __restrict__ W,
    const float* __restrict__ bias, float* __restrict__ outp)
{
  const int K = DD, N = DD;
  const int row0 = blockIdx.x * 64;
  const int h    = blockIdx.y;
  const int col0 = h << 6;
  const int tid = threadIdx.x;
  const int ty = tid >> 4, tx = tid & 15;

  __shared__ __align__(16) float As[16 * 64];
  __shared__ __align__(16) float Bs[16 * 64];

  float acc[4][4] = {};
  for (int k0 = 0; k0 < K; k0 += 16) {
    {
      int r = tid >> 2, c = (tid & 3) << 2;
      float4 a4 = *(const float4*)&X[(size_t)(row0 + r) * K + k0 + c];
      As[(c + 0) * 64 + r] = a4.x; As[(c + 1) * 64 + r] = a4.y;
      As[(c + 2) * 64 + r] = a4.z; As[(c + 3) * 64 + r] = a4.w;
    }
    {
      int r = tid >> 4, c = (tid & 15) << 2;
      *(float4*)&Bs[r * 64 + c] = *(const float4*)&W[(size_t)(k0 + r) * N + col0 + c];
    }
    __syncthreads();
#pragma unroll
    for (int kk = 0; kk < 16; ++kk) {
      float4 a4 = *(float4*)&As[kk * 64 + ty * 4];
      float4 b4 = *(float4*)&Bs[kk * 64 + tx * 4];
      float a[4] = {a4.x, a4.y, a4.z, a4.w};
      float b[4] = {b4.x, b4.y, b4.z, b4.w};
#pragma unroll
      for (int i = 0; i < 4; i++)
#pragma unroll
        for (int j = 0; j < 4; j++) acc[i][j] += a[i] * b[j];
    }
    __syncthreads();
  }
  float4 bv4 = *(const float4*)&bias[col0 + tx * 4];
#pragma unroll
  for (int i = 0; i < 4; i++) {
    int row = row0 + ty * 4 + i;
    int b = row >> 11, s = row & (SS - 1);
    float4 o;
    o.x = acc[i][0] + bv4.x; o.y = acc[i][1] + bv4.y;
    o.z = acc[i][2] + bv4.z; o.w = acc[i][3] + bv4.w;
    *(float4*)&outp[(((size_t)b * HH + h) * SS + s) * DKV + tx * 4] = o;
  }
}

// ---------------------------------------------------------------------------
// Output projection (unchanged, fp32)
// ---------------------------------------------------------------------------
__global__ __launch_bounds__(256) void outproj_gemm(
    const float* __restrict__ X, const float* __restrict__ W,
    const float* __restrict__ bias, const float* __restrict__ resid,
    float* __restrict__ outp)
{
  const int K = DD, N = DD;
  const int row0 = blockIdx.x * 64;
  const int col0 = blockIdx.y << 6;
  const int tid = threadIdx.x;
  const int ty = tid >> 4, tx = tid & 15;

  __shared__ __align__(16) float As[16 * 64];
  __shared__ __align__(16) float Bs[16 * 64];

  float acc[4][4] = {};
  for (int k0 = 0; k0 < K; k0 += 16) {
    {
      int r = tid >> 2, c = (tid & 3) << 2;
      float4 a4 = *(const float4*)&X[(size_t)(row0 + r) * K + k0 + c];
      As[(c + 0) * 64 + r] = a4.x; As[(c + 1) * 64 + r] = a4.y;
      As[(c + 2) * 64 + r] = a4.z; As[(c + 3) * 64 + r] = a4.w;
    }
    {
      int r = tid >> 4, c = (tid & 15) << 2;
      *(float4*)&Bs[r * 64 + c] = *(const float4*)&W[(size_t)(k0 + r) * N + col0 + c];
    }
    __syncthreads();
#pragma unroll
    for (int kk = 0; kk < 16; ++kk) {
      float4 a4 = *(float4*)&As[kk * 64 + ty * 4];
      float4 b4 = *(float4*)&Bs[kk * 64 + tx * 4];
      float a[4] = {a4.x, a4.y, a4.z, a4.w};
      float b[4] = {b4.x, b4.y, b4.z, b4.w};
#pragma unroll
      for (int i = 0; i < 4; i++)
#pragma unroll
        for (int j = 0; j < 4; j++) acc[i][j] += a[i] * b[j];
    }
    __syncthreads();
  }
  float4 bv4 = *(const float4*)&bias[col0 + tx * 4];
#pragma unroll
  for (int i = 0; i < 4; i++) {
    int row = row0 + ty * 4 + i;
    float4 r4 = *(const float4*)&resid[(size_t)row * DD + col0 + tx * 4];
    float4 o;
    o.x = acc[i][0] + bv4.x + r4.x; o.y = acc[i][1] + bv4.y + r4.y;
    o.z = acc[i][2] + bv4.z + r4.z; o.w = acc[i][3] + bv4.w + r4.w;
    *(float4*)&outp[(size_t)row * DD + col0 + tx * 4] = o;
  }
}

// ---------------------------------------------------------------------------
// MFMA attention. Block = 256 thr = 4 waves; one block per (b, h, 64-q tile).
// Wave w owns the 16-query strip [16w, 16w+16).
// LDS tiles bf16 row-major, 128B rows, XOR-swizzle byte ^= (row&7)<<4.
// ---------------------------------------------------------------------------
__device__ inline bf16x8 ldfrag(const short* base, int row, int bytecol) {
  int off = row * 128 + (bytecol ^ ((row & 7) << 4));
  return *(const bf16x8*)((const char*)base + off);
}

// stage [64][64] f32 row-major -> bf16 swizzled rows (128B each)
__device__ inline void stage_rows64(const float* __restrict__ src, short* dst, int tid) {
#pragma unroll
  for (int j = 0; j < 4; ++j) {
    int li = j * 256 + tid;          // float4 linear index, fully coalesced
    int row = li >> 4;
    int c4 = (li & 15) << 2;
    f32x4 v = *(const f32x4*)(src + row * 64 + c4);
    s16x4 o;
    o[0] = (short)f2bf(v[0]); o[1] = (short)f2bf(v[1]);
    o[2] = (short)f2bf(v[2]); o[3] = (short)f2bf(v[3]);
    int off = row * 128 + (((c4) << 1) ^ ((row & 7) << 4));
    *(s16x4*)((char*)dst + off) = o;
  }
}

// stage V chunk [64key][64dv] f32 -> Vt bf16 [dv][key] swizzled
__device__ inline void stage_vt(const float* __restrict__ vsrc, short* dst, int tid) {
  int kb = tid >> 4;   // keys 4kb..4kb+4
  int db = tid & 15;   // dv 4db..4db+4
  const float* p0 = vsrc + (size_t)(4 * kb) * 64 + 4 * db;
  f32x4 r0 = *(const f32x4*)(p0);
  f32x4 r1 = *(const f32x4*)(p0 + 64);
  f32x4 r2 = *(const f32x4*)(p0 + 128);
  f32x4 r3 = *(const f32x4*)(p0 + 192);
#pragma unroll
  for (int i = 0; i < 4; ++i) {
    s16x4 o;
    o[0] = (short)f2bf(r0[i]); o[1] = (short)f2bf(r1[i]);
    o[2] = (short)f2bf(r2[i]); o[3] = (short)f2bf(r3[i]);
    int row = 4 * db + i;            // dv row in Vt
    int off = row * 128 + ((kb * 8) ^ ((row & 7) << 4));
    *(s16x4*)((char*)dst + off) = o;
  }
}

__global__ __launch_bounds__(256) void attn_mfma(
    const float* __restrict__ qh, const float* __restrict__ kh,
    const float* __restrict__ vh, const int* __restrict__ pad,
    float* __restrict__ attn, float* __restrict__ ctx)
{
  const int qt = blockIdx.x, h = blockIdx.y, b = blockIdx.z;
  const int tid = threadIdx.x;
  const int lane = tid & 63, w = tid >> 6;
  const int c = lane & 15, g = lane >> 4;

  __shared__ __align__(16) short Qs[64 * 64];
  __shared__ __align__(16) short KsS[64 * 64];
  __shared__ __align__(16) short VtS[64 * 64];
  __shared__ __align__(16) short PsS[64 * 64];   // 4 strips of [16][64]

  const float* qbase = qh + (((size_t)b * HH + h) * SS + (size_t)qt * 64) * DKV;
  const float* kbase = kh + (((size_t)b * HH + h) * SS) * DKV;
  const float* vbase = vh + (((size_t)b * HH + h) * SS) * DKV;

  stage_rows64(qbase, Qs, tid);
  __syncthreads();

  // Q fragments for this wave's strip: A row = lane&15, 8 contiguous d per lane
  const bf16x8 aq0 = ldfrag(Qs, 16 * w + c, g * 16);
  const bf16x8 aq1 = ldfrag(Qs, 16 * w + c, 64 + g * 16);

  const int q0 = qt * 64 + 16 * w;   // first global q row of this wave's strip

  float mrun[4] = {NEGBIG, NEGBIG, NEGBIG, NEGBIG};
  float lrun[4] = {0.f, 0.f, 0.f, 0.f};

  // ---------------- pass 1: online (m, l) ----------------
  for (int kc = 0; kc < SS / 64; ++kc) {
    const int kc0 = kc << 6;
    __syncthreads();
    stage_rows64(kbase + (size_t)kc0 * DKV, KsS, tid);
    __syncthreads();

    f32x4 accS[4] = {{0.f,0.f,0.f,0.f},{0.f,0.f,0.f,0.f},{0.f,0.f,0.f,0.f},{0.f,0.f,0.f,0.f}};
#pragma unroll
    for (int nt = 0; nt < 4; ++nt) {
      bf16x8 b0 = ldfrag(KsS, 16 * nt + c, g * 16);
      bf16x8 b1 = ldfrag(KsS, 16 * nt + c, 64 + g * 16);
      accS[nt] = __builtin_amdgcn_mfma_f32_16x16x32_bf16(aq0, b0, accS[nt], 0, 0, 0);
      accS[nt] = __builtin_amdgcn_mfma_f32_16x16x32_bf16(aq1, b1, accS[nt], 0, 0, 0);
    }

    float sc[4][4];
    float cmax[4] = {NEGBIG, NEGBIG, NEGBIG, NEGBIG};
#pragma unroll
    for (int r = 0; r < 4; ++r) {
      const int* prow = pad + ((size_t)b * SS + (q0 + 4 * g + r)) * SS + kc0 + c;
#pragma unroll
      for (int nt = 0; nt < 4; ++nt) {
        float s = accS[nt][r] * 0.125f;
        s = prow[16 * nt] ? -1e9f : s;
        sc[r][nt] = s;
        cmax[r] = fmaxf(cmax[r], s);
      }
    }
#pragma unroll
    for (int r = 0; r < 4; ++r) {
#pragma unroll
      for (int m = 1; m <= 8; m <<= 1)
        cmax[r] = fmaxf(cmax[r], __shfl_xor(cmax[r], m));
      float mn = fmaxf(mrun[r], cmax[r]);
      float corr = __expf(mrun[r] - mn);
      float ps = 0.f;
#pragma unroll
      for (int nt = 0; nt < 4; ++nt) ps += __expf(sc[r][nt] - mn);
#pragma unroll
      for (int m = 1; m <= 8; m <<= 1) ps += __shfl_xor(ps, m);
      lrun[r] = lrun[r] * corr + ps;
      mrun[r] = mn;
    }
  }

  float linv[4];
#pragma unroll
  for (int r = 0; r < 4; ++r) linv[r] = 1.f / lrun[r];

  f32x4 cacc[4] = {{0.f,0.f,0.f,0.f},{0.f,0.f,0.f,0.f},{0.f,0.f,0.f,0.f},{0.f,0.f,0.f,0.f}};
  float* attb = attn + ((size_t)b * HH + h) * SS * SS;

  // ---------------- pass 2: write attn + PV ----------------
  for (int kc = 0; kc < SS / 64; ++kc) {
    const int kc0 = kc << 6;
    __syncthreads();
    stage_rows64(kbase + (size_t)kc0 * DKV, KsS, tid);
    stage_vt(vbase + (size_t)kc0 * DKV, VtS, tid);
    __syncthreads();

    f32x4 accS[4] = {{0.f,0.f,0.f,0.f},{0.f,0.f,0.f,0.f},{0.f,0.f,0.f,0.f},{0.f,0.f,0.f,0.f}};
#pragma unroll
    for (int nt = 0; nt < 4; ++nt) {
      bf16x8 b0 = ldfrag(KsS, 16 * nt + c, g * 16);
      bf16x8 b1 = ldfrag(KsS, 16 * nt + c, 64 + g * 16);
      accS[nt] = __builtin_amdgcn_mfma_f32_16x16x32_bf16(aq0, b0, accS[nt], 0, 0, 0);
      accS[nt] = __builtin_amdgcn_mfma_f32_16x16x32_bf16(aq1, b1, accS[nt], 0, 0, 0);
    }

#pragma unroll
    for (int r = 0; r < 4; ++r) {
      const int q = q0 + 4 * g + r;
      const int* prow = pad + ((size_t)b * SS + q) * SS + kc0 + c;
      float* arow = attb + (size_t)q * SS + kc0 + c;
      const int psrow = 4 * g + r;
#pragma unroll
      for (int nt = 0; nt < 4; ++nt) {
        float s = accS[nt][r] * 0.125f;
        s = prow[16 * nt] ? -1e9f : s;
        float p = __expf(s - mrun[r]) * linv[r];
        arow[16 * nt] = p;                                   // final normalized attn (f32)
        int off = w * 2048 + psrow * 128 + ((((16 * nt + c) << 1)) ^ ((psrow & 7) << 4));
        *(short*)((char*)PsS + off) = (short)f2bf(p);
      }
    }
    // wave-local: P strip written above is read below by the same wave
    asm volatile("s_waitcnt lgkmcnt(0)" ::: "memory");
    __builtin_amdgcn_sched_barrier(0);

    const bf16x8 pa0 = *(const bf16x8*)((const char*)PsS + w * 2048 + c * 128 + ((g * 16) ^ ((c & 7) << 4)));
    const bf16x8 pa1 = *(const bf16x8*)((const char*)PsS + w * 2048 + c * 128 + ((64 + g * 16) ^ ((c & 7) << 4)));
#pragma unroll
    for (int nt = 0; nt < 4; ++nt) {
      bf16x8 v0 = ldfrag(VtS, 16 * nt + c, g * 16);
      bf16x8 v1 = ldfrag(VtS, 16 * nt + c, 64 + g * 16);
      cacc[nt] = __builtin_amdgcn_mfma_f32_16x16x32_bf16(pa0, v0, cacc[nt], 0, 0, 0);
      cacc[nt] = __builtin_amdgcn_mfma_f32_16x16x32_bf16(pa1, v1, cacc[nt], 0, 0, 0);
    }
  }

  // write context in [B,S,H*DV] layout
#pragma unroll
  for (int r = 0; r < 4; ++r) {
    int row = q0 + 4 * g + r;
    float* crow = ctx + ((size_t)b * SS + row) * DD + h * DKV + c;
#pragma unroll
    for (int nt = 0; nt < 4; ++nt) crow[16 * nt] = cacc[nt][r];
  }
}

// ---------------------------------------------------------------------------
// LayerNorm over last dim (768), one block (256 thr) per row.
// ---------------------------------------------------------------------------
__global__ __launch_bounds__(256) void ln_kernel(
    const float* __restrict__ x, const float* __restrict__ gam,
    const float* __restrict__ bet, float* __restrict__ out)
{
  const int row = blockIdx.x;
  const int tid = threadIdx.x;
  const float* xr = x + (size_t)row * DD;
  float v0 = xr[tid], v1 = xr[tid + 256], v2 = xr[tid + 512];
  float s1 = v0 + v1 + v2;
  float s2 = v0 * v0 + v1 * v1 + v2 * v2;
  __shared__ float r1[256], r2[256];
  r1[tid] = s1; r2[tid] = s2;
  __syncthreads();
  for (int off = 128; off > 0; off >>= 1) {
    if (tid < off) { r1[tid] += r1[tid + off]; r2[tid] += r2[tid + off]; }
    __syncthreads();
  }
  __shared__ float mu_s, rs_s;
  if (tid == 0) {
    float mu = r1[0] * (1.f / 768.f);
    float var = r2[0] * (1.f / 768.f) - mu * mu;
    mu_s = mu; rs_s = rsqrtf(var + 1e-5f);
  }
  __syncthreads();
  float mu = mu_s, rs = rs_s;
  float* orow = out + (size_t)row * DD;
  orow[tid]       = (v0 - mu) * rs * gam[tid]       + bet[tid];
  orow[tid + 256] = (v1 - mu) * rs * gam[tid + 256] + bet[tid + 256];
  orow[tid + 512] = (v2 - mu) * rs * gam[tid + 512] + bet[tid + 512];
}

// ---------------------------------------------------------------------------
extern "C" void kernel_launch(void* const* d_in, const int* in_sizes, int n_in,
                              void* d_out, int out_size, void* d_ws, size_t ws_size,
                              hipStream_t stream) {
  const float* Q   = (const float*)d_in[0];
  const float* K   = (const float*)d_in[1];
  const float* V   = (const float*)d_in[2];
  const int*   pad = (const int*)d_in[3];
  const float* Wq  = (const float*)d_in[4];
  const float* bq  = (const float*)d_in[5];
  const float* Wk  = (const float*)d_in[6];
  const float* bk  = (const float*)d_in[7];
  const float* Wv  = (const float*)d_in[8];
  const float* bv  = (const float*)d_in[9];
  const float* Wo  = (const float*)d_in[10];
  const float* bo  = (const float*)d_in[11];
  const float* lng = (const float*)d_in[12];
  const float* lnb = (const float*)d_in[13];

  float* out  = (float*)d_out;                       // [B,S,D]
  float* attn = out + (size_t)BB * SS * DD;          // [B,H,S,S]

  const size_t NQ = (size_t)BB * SS * DD;            // 6291456
  float* ws  = (float*)d_ws;
  float* qh  = ws;                                    // [B,H,S,64]
  float* khp = ws + NQ;
  float* vhp = ws + 2 * NQ;
  float* ctx = ws + 3 * NQ;                           // [B,S,768]
  float* tmp = qh;                                    // reuse (qh dead after attn)

  dim3 gproj(SS * BB / 64, DD / 64);                  // (128, 12)
  proj_gemm<<<gproj, 256, 0, stream>>>(Q, Wq, bq, qh);
  proj_gemm<<<gproj, 256, 0, stream>>>(K, Wk, bk, khp);
  proj_gemm<<<gproj, 256, 0, stream>>>(V, Wv, bv, vhp);

  dim3 gattn(SS / 64, HH, BB);                        // (32, 12, 4)
  attn_mfma<<<gattn, 256, 0, stream>>>(qh, khp, vhp, pad, attn, ctx);

  outproj_gemm<<<gproj, 256, 0, stream>>>(ctx, Wo, bo, Q, tmp);

  ln_kernel<<<BB * SS, 256, 0, stream>>>(tmp, lng, lnb, out);
}